// Round 2
// baseline (141.933 us; speedup 1.0000x reference)
//
#include <hip/hip_runtime.h>
#include <math.h>

#define A_N 5
#define NC 20
#define FD 38
#define SD (FD*FD)        // 1444
#define BD 32
#define OD 50
#define SA (SD*A_N)       // 7220
#define IGN_T 0.6f
#define OBJ_S 5.0f

__device__ __forceinline__ float sigm(float x) { return 1.0f / (1.0f + expf(-x)); }

// ---------------- Kernel A: max IoU per (b,s,a) ------------------------------
// Also zeroes d_out (runs strictly before k_loss in stream order).
__global__ __launch_bounds__(256) void k_maxiou(
    const float* __restrict__ outputs, const float* __restrict__ targets,
    const float* __restrict__ anchors, float* __restrict__ miou,
    float* __restrict__ out)
{
    __shared__ float g_tlx[OD], g_tly[OD], g_brx[OD], g_bry[OD], g_den[OD];
    __shared__ int s_cnt;
    const int b = blockIdx.y;
    const int tid = threadIdx.x;
    if (blockIdx.x == 0 && b == 0 && tid == 0) *out = 0.0f;
    if (tid == 0) s_cnt = 0;
    __syncthreads();
    if (tid < OD) {
        const float* t = targets + (b * OD + tid) * 5;
        float tx = t[0], ty = t[1], tw = t[2], th = t[3], tc = t[4];
        if (tx + ty + tw + th + tc > 0.0f) {
            float gx = tx * FD, gy = ty * FD, gw = tw * FD, gh = th * FD;
            int k = atomicAdd(&s_cnt, 1);
            g_tlx[k] = gx - gw * 0.5f; g_tly[k] = gy - gh * 0.5f;
            g_brx[k] = gx + gw * 0.5f; g_bry[k] = gy + gh * 0.5f;
            g_den[k] = gw * gh + 1e-12f;   // area_b + eps
        }
    }
    __syncthreads();
    const int cnt = s_cnt;
    const int idx = blockIdx.x * 256 + tid;
    if (idx >= SA) return;
    const int a = idx / SD;
    const int s = idx - a * SD;
    const int i = s / FD, j = s - i * FD;

    const float* ob = outputs + ((size_t)b * (A_N * (5 + NC)) + a * (5 + NC)) * SD + s;
    float o0 = ob[0 * SD], o1 = ob[1 * SD], o2 = ob[2 * SD], o3 = ob[3 * SD];
    float aw = anchors[2 * a] * FD, ah = anchors[2 * a + 1] * FD;
    float px = sigm(o0) + (float)j;
    float py = sigm(o1) + (float)i;
    float pw = expf(o2) * aw;
    float ph = expf(o3) * ah;
    float ptlx = px - pw * 0.5f, ptly = py - ph * 0.5f;
    float pbrx = px + pw * 0.5f, pbry = py + ph * 0.5f;
    float areaA = pw * ph;

    float m = 0.0f;
    for (int o = 0; o < cnt; ++o) {
        float w = fmaxf(fminf(pbrx, g_brx[o]) - fmaxf(ptlx, g_tlx[o]), 0.0f);
        float h = fmaxf(fminf(pbry, g_bry[o]) - fmaxf(ptly, g_tly[o]), 0.0f);
        float inter = w * h;
        float iou = inter / (areaA + g_den[o] - inter);
        m = fmaxf(m, iou);
    }
    miou[(size_t)b * SA + idx] = m;
}

// ---------------- Kernel B: loss, one block per batch ------------------------
// Recomputes the (cell,anchor) assignment in-block (trivial: 50 obj x 5
// anchors), builds a direct-map LDS table with numpy last-write-wins
// (thread 0 fills in ascending o), computes n_pos in-block, then the loss.
__global__ __launch_bounds__(256) void k_loss(
    const float* __restrict__ outputs, const float* __restrict__ targets,
    const float* __restrict__ anchors, const float* __restrict__ miou,
    float* __restrict__ out)
{
    __shared__ signed char table[SA];              // key -> object index (or -1)
    __shared__ int   s_key[OD];
    __shared__ float s_gx[OD], s_gy[OD], s_gw[OD], s_gh[OD];
    __shared__ int   s_cls[OD];
    __shared__ int   s_npos;
    __shared__ float wsum[4];

    const int b = blockIdx.x;
    const int tid = threadIdx.x;
    if (tid == 0) s_npos = 0;
    for (int i = tid; i < SA; i += 256) table[i] = -1;

    if (tid < OD) {
        const float* t = targets + (b * OD + tid) * 5;
        float tx = t[0], ty = t[1], tw = t[2], th = t[3], tc = t[4];
        int key = -1;
        if (tx + ty + tw + th + tc > 0.0f) {
            float gx = tx * FD, gy = ty * FD, gw = tw * FD, gh = th * FD;
            float gtlx = gx - gw * 0.5f, gtly = gy - gh * 0.5f;
            float gbrx = gx + gw * 0.5f, gbry = gy + gh * 0.5f;
            int cx = (int)floorf(gtlx), cy = (int)floorf(gtly);
            int cell = min(max(cy * FD + cx, 0), SD - 1);
            int ci = cell / FD, cj = cell - ci * FD;
            float acx = (float)cj + 0.5f, acy = (float)ci + 0.5f;
            float areaB = gw * gh;
            float best = -1.0f; int bi = 0;
            for (int a = 0; a < A_N; ++a) {
                float aw = anchors[2 * a] * FD, ah = anchors[2 * a + 1] * FD;
                float w = fmaxf(fminf(acx + aw * 0.5f, gbrx) - fmaxf(acx - aw * 0.5f, gtlx), 0.0f);
                float h = fmaxf(fminf(acy + ah * 0.5f, gbry) - fmaxf(acy - ah * 0.5f, gtly), 0.0f);
                float inter = w * h;
                float iou = inter / (aw * ah + areaB - inter + 1e-12f);
                if (iou > best) { best = iou; bi = a; }
            }
            key = bi * SD + cell;
            s_gx[tid] = gx; s_gy[tid] = gy; s_gw[tid] = gw; s_gh[tid] = gh;
            s_cls[tid] = (int)tc;
        }
        s_key[tid] = key;
    }
    __syncthreads();
    // last-write-wins: serial fill in ascending o (matches numpy fancy assign)
    if (tid == 0) {
        for (int o = 0; o < OD; ++o)
            if (s_key[o] >= 0) table[s_key[o]] = (signed char)o;
    }
    // n_pos pass (overlaps thread 0's table fill)
    const float* mb = miou + (size_t)b * SA;
    int any = 0;
    for (int idx = tid; idx < SA; idx += 256) any |= (mb[idx] > IGN_T) ? 1 : 0;
    if (any) atomicOr(&s_npos, 1);
    __syncthreads();
    const int np = s_npos;

    const float* obase = outputs + (size_t)b * (A_N * (5 + NC)) * SD;
    float loss = 0.0f;
    for (int idx = tid; idx < SA; idx += 256) {
        const int a = idx / SD;
        const int s = idx - a * SD;
        const float m = mb[idx];
        const float* ob = obase + (a * (5 + NC)) * SD + s;
        float conf = sigm(ob[4 * SD]);
        int ro = table[idx];                       // key == a*SD + s == idx
        if (ro >= 0) {
            // iou loss at responsible position: mask = OBJ_SCALE, target = m
            float d = conf - m;
            loss += OBJ_S * OBJ_S * d * d;
            // box loss: pd = [sigm, sigm, exp, exp] (NO anchor scale on pd)
            const int i = s / FD, j = s - i * FD;
            float aw = anchors[2 * a] * FD, ah = anchors[2 * a + 1] * FD;
            float dx = s_gx[ro] - ((float)j + 0.5f);
            float dy = s_gy[ro] - ((float)i + 0.5f);
            float dw = s_gw[ro] / aw;
            float dh = s_gh[ro] / ah;
            float e0 = sigm(ob[0])      - dx;
            float e1 = sigm(ob[SD])     - dy;
            float e2 = expf(ob[2 * SD]) - dw;
            float e3 = expf(ob[3 * SD]) - dh;
            loss += e0*e0 + e1*e1 + e2*e2 + e3*e3;
            // class loss: ce = -log_softmax(softmax(x))[ct]
            int ct = s_cls[ro];
            float x[NC];
            float xmax = -INFINITY;
            #pragma unroll
            for (int k = 0; k < NC; ++k) { x[k] = ob[(5 + k) * SD]; xmax = fmaxf(xmax, x[k]); }
            float esum = 0.0f;
            #pragma unroll
            for (int k = 0; k < NC; ++k) { x[k] = expf(x[k] - xmax); esum += x[k]; }
            float inv = 1.0f / esum;
            float pmax = 0.0f, pct = 0.0f;
            #pragma unroll
            for (int k = 0; k < NC; ++k) {
                float p = x[k] * inv; x[k] = p;
                pmax = fmaxf(pmax, p);
                pct = (k == ct) ? p : pct;
            }
            float e2s = 0.0f;
            #pragma unroll
            for (int k = 0; k < NC; ++k) e2s += expf(x[k] - pmax);
            loss += -(pct - (pmax + logf(e2s)));
        } else {
            bool ign = (np != 0) && (m >= IGN_T);
            if (!ign) loss += conf * conf;         // (conf*1 - 0)^2
        }
    }

    // block reduction: wave64 shuffle + LDS across 4 waves
    #pragma unroll
    for (int off = 32; off > 0; off >>= 1) loss += __shfl_down(loss, off);
    int lane = tid & 63, w = tid >> 6;
    if (lane == 0) wsum[w] = loss;
    __syncthreads();
    if (tid == 0) {
        float t = wsum[0] + wsum[1] + wsum[2] + wsum[3];
        atomicAdd(out, t * (1.0f / (float)BD));
    }
}

extern "C" void kernel_launch(void* const* d_in, const int* in_sizes, int n_in,
                              void* d_out, int out_size, void* d_ws, size_t ws_size,
                              hipStream_t stream) {
    (void)in_sizes; (void)n_in; (void)out_size; (void)ws_size;
    const float* outputs = (const float*)d_in[0];
    const float* targets = (const float*)d_in[1];
    const float* anchors = (const float*)d_in[2];
    float* out = (float*)d_out;
    float* miou = (float*)d_ws;                    // B*S*A floats = 924 KB

    dim3 grid((SA + 255) / 256, BD);
    k_maxiou<<<grid, 256, 0, stream>>>(outputs, targets, anchors, miou, out);
    k_loss<<<dim3(BD), 256, 0, stream>>>(outputs, targets, anchors, miou, out);
}

// Round 3
// 85.984 us; speedup vs baseline: 1.6507x; 1.6507x over previous
//
#include <hip/hip_runtime.h>
#include <math.h>

#define A_N 5
#define NC 20
#define FD 38
#define SD (FD*FD)        // 1444
#define BD 32
#define OD 50
#define SA (SD*A_N)       // 7220
#define GX ((SA + 255) / 256)   // 29 blocks per batch
#define IGN_T 0.6f
#define OBJ_S 5.0f

__device__ __forceinline__ float sigm(float x) { return 1.0f / (1.0f + expf(-x)); }

// ---------------- Kernel 1: fused max-IoU + responsibility + speculative loss
// grid (GX, BD). Per block: stage GT boxes + responsibility keys in LDS,
// then each thread handles one (s,a) position. Loss is split:
//   base = contributions valid when n_pos[b]==1 (+ all responsible terms)
//   corr = conf^2 at ignored (m>=0.6) non-responsible positions (added iff n_pos==0)
// Per-block partials stored to distinct slots (plain stores, no init needed).
__global__ __launch_bounds__(256) void k_main(
    const float* __restrict__ outputs, const float* __restrict__ targets,
    const float* __restrict__ anchors,
    float* __restrict__ pbase, float* __restrict__ pcorr, int* __restrict__ pflag)
{
    __shared__ float g_tlx[OD], g_tly[OD], g_brx[OD], g_bry[OD], g_den[OD];
    __shared__ int   s_cnt, s_any;
    __shared__ int   s_key[OD], s_cls[OD];
    __shared__ float s_gx[OD], s_gy[OD], s_gw[OD], s_gh[OD];
    __shared__ float wb[4], wc[4];

    const int b = blockIdx.y;
    const int tid = threadIdx.x;
    if (tid == 0) { s_cnt = 0; s_any = 0; }
    __syncthreads();

    if (tid < OD) {
        const float* t = targets + (b * OD + tid) * 5;
        float tx = t[0], ty = t[1], tw = t[2], th = t[3], tc = t[4];
        int key = -1;
        if (tx + ty + tw + th + tc > 0.0f) {
            float gx = tx * FD, gy = ty * FD, gw = tw * FD, gh = th * FD;
            float gtlx = gx - gw * 0.5f, gtly = gy - gh * 0.5f;
            float gbrx = gx + gw * 0.5f, gbry = gy + gh * 0.5f;
            // compacted box list for the max-IoU loop
            int k = atomicAdd(&s_cnt, 1);
            g_tlx[k] = gtlx; g_tly[k] = gtly;
            g_brx[k] = gbrx; g_bry[k] = gbry;
            g_den[k] = gw * gh + 1e-12f;
            // responsibility key: cell + argmax-anchor
            int cx = (int)floorf(gtlx), cy = (int)floorf(gtly);
            int cell = min(max(cy * FD + cx, 0), SD - 1);
            int ci = cell / FD, cj = cell - ci * FD;
            float acx = (float)cj + 0.5f, acy = (float)ci + 0.5f;
            float areaB = gw * gh;
            float best = -1.0f; int bi = 0;
            for (int a = 0; a < A_N; ++a) {
                float aw = anchors[2 * a] * FD, ah = anchors[2 * a + 1] * FD;
                float w = fmaxf(fminf(acx + aw * 0.5f, gbrx) - fmaxf(acx - aw * 0.5f, gtlx), 0.0f);
                float h = fmaxf(fminf(acy + ah * 0.5f, gbry) - fmaxf(acy - ah * 0.5f, gtly), 0.0f);
                float inter = w * h;
                float iou = inter / (aw * ah + areaB - inter + 1e-12f);
                if (iou > best) { best = iou; bi = a; }
            }
            key = bi * SD + cell;
            s_gx[tid] = gx; s_gy[tid] = gy; s_gw[tid] = gw; s_gh[tid] = gh;
            s_cls[tid] = (int)tc;
        }
        s_key[tid] = key;
    }
    __syncthreads();
    const int cnt = s_cnt;

    const int idx = blockIdx.x * 256 + tid;
    float base = 0.0f, corr = 0.0f;
    bool hot = false;
    if (idx < SA) {
        const int a = idx / SD;
        const int s = idx - a * SD;
        const int i = s / FD, j = s - i * FD;
        const float* ob = outputs + ((size_t)b * (A_N * (5 + NC)) + a * (5 + NC)) * SD + s;
        float o0 = ob[0 * SD], o1 = ob[1 * SD], o2 = ob[2 * SD], o3 = ob[3 * SD];
        float cr = ob[4 * SD];
        float aw = anchors[2 * a] * FD, ah = anchors[2 * a + 1] * FD;
        float px = sigm(o0) + (float)j;
        float py = sigm(o1) + (float)i;
        float pw = expf(o2) * aw;
        float ph = expf(o3) * ah;
        float ptlx = px - pw * 0.5f, ptly = py - ph * 0.5f;
        float pbrx = px + pw * 0.5f, pbry = py + ph * 0.5f;
        float areaA = pw * ph;

        float m = 0.0f;
        for (int o = 0; o < cnt; ++o) {
            float w = fmaxf(fminf(pbrx, g_brx[o]) - fmaxf(ptlx, g_tlx[o]), 0.0f);
            float h = fmaxf(fminf(pbry, g_bry[o]) - fmaxf(ptly, g_tly[o]), 0.0f);
            float inter = w * h;
            float iou = inter / (areaA + g_den[o] - inter);
            m = fmaxf(m, iou);
        }
        hot = (m > IGN_T);                       // strict >, for n_pos

        // responsibility: last match wins (ascending o == numpy fancy assign)
        int ro = -1;
        #pragma unroll 10
        for (int o = 0; o < OD; ++o) ro = (s_key[o] == idx) ? o : ro;

        float conf = sigm(cr);
        if (ro >= 0) {
            float d = conf - m;                  // iou loss, mask = OBJ_SCALE
            base += OBJ_S * OBJ_S * d * d;
            // box loss: pd = [sigm, sigm, exp, exp] (NO anchor scale on pd)
            float dx = s_gx[ro] - ((float)j + 0.5f);
            float dy = s_gy[ro] - ((float)i + 0.5f);
            float dw = s_gw[ro] / aw;
            float dh = s_gh[ro] / ah;
            float e0 = sigm(o0) - dx;
            float e1 = sigm(o1) - dy;
            float e2 = expf(o2) - dw;
            float e3 = expf(o3) - dh;
            base += e0*e0 + e1*e1 + e2*e2 + e3*e3;
            // class loss: ce = -log_softmax(softmax(x))[ct]
            int ct = s_cls[ro];
            float x[NC];
            float xmax = -INFINITY;
            #pragma unroll
            for (int k = 0; k < NC; ++k) { x[k] = ob[(5 + k) * SD]; xmax = fmaxf(xmax, x[k]); }
            float esum = 0.0f;
            #pragma unroll
            for (int k = 0; k < NC; ++k) { x[k] = expf(x[k] - xmax); esum += x[k]; }
            float inv = 1.0f / esum;
            float pmax = 0.0f, pct = 0.0f;
            #pragma unroll
            for (int k = 0; k < NC; ++k) {
                float p = x[k] * inv; x[k] = p;
                pmax = fmaxf(pmax, p);
                pct = (k == ct) ? p : pct;
            }
            float e2s = 0.0f;
            #pragma unroll
            for (int k = 0; k < NC; ++k) e2s += expf(x[k] - pmax);
            base += -(pct - (pmax + logf(e2s)));
        } else {
            float c2 = conf * conf;              // (conf*1 - 0)^2
            if (m < IGN_T) base += c2;           // kept even when n_pos==1
            else           corr += c2;           // only counts if n_pos==0
        }
    }

    unsigned long long bal = __ballot(hot);
    if ((tid & 63) == 0 && bal) atomicOr(&s_any, 1);

    // block reduction of (base, corr): wave64 shuffle + LDS across 4 waves
    #pragma unroll
    for (int off = 32; off > 0; off >>= 1) {
        base += __shfl_down(base, off);
        corr += __shfl_down(corr, off);
    }
    int lane = tid & 63, w = tid >> 6;
    if (lane == 0) { wb[w] = base; wc[w] = corr; }
    __syncthreads();
    if (tid == 0) {
        int gid = b * GX + blockIdx.x;
        pbase[gid] = wb[0] + wb[1] + wb[2] + wb[3];
        pcorr[gid] = wc[0] + wc[1] + wc[2] + wc[3];
        pflag[gid] = s_any;
    }
}

// ---------------- Kernel 2: combine partials ---------------------------------
__global__ __launch_bounds__(256) void k_finish(
    const float* __restrict__ pbase, const float* __restrict__ pcorr,
    const int* __restrict__ pflag, float* __restrict__ out)
{
    __shared__ int npos[BD];
    __shared__ float wsum[4];
    const int tid = threadIdx.x;
    if (tid < BD) {
        int f = 0;
        for (int x = 0; x < GX; ++x) f |= pflag[tid * GX + x];
        npos[tid] = f;
    }
    __syncthreads();
    float sum = 0.0f;
    for (int g = tid; g < BD * GX; g += 256) {
        int b = g / GX;
        sum += pbase[g] + (npos[b] ? 0.0f : pcorr[g]);
    }
    #pragma unroll
    for (int off = 32; off > 0; off >>= 1) sum += __shfl_down(sum, off);
    int lane = tid & 63, w = tid >> 6;
    if (lane == 0) wsum[w] = sum;
    __syncthreads();
    if (tid == 0) out[0] = (wsum[0] + wsum[1] + wsum[2] + wsum[3]) * (1.0f / (float)BD);
}

extern "C" void kernel_launch(void* const* d_in, const int* in_sizes, int n_in,
                              void* d_out, int out_size, void* d_ws, size_t ws_size,
                              hipStream_t stream) {
    (void)in_sizes; (void)n_in; (void)out_size; (void)ws_size;
    const float* outputs = (const float*)d_in[0];
    const float* targets = (const float*)d_in[1];
    const float* anchors = (const float*)d_in[2];
    float* out = (float*)d_out;

    const int G = BD * GX;                        // 928 partial slots
    float* pbase = (float*)d_ws;
    float* pcorr = pbase + G;
    int*   pflag = (int*)(pcorr + G);

    k_main<<<dim3(GX, BD), 256, 0, stream>>>(outputs, targets, anchors,
                                             pbase, pcorr, pflag);
    k_finish<<<dim3(1), 256, 0, stream>>>(pbase, pcorr, pflag, out);
}